// Round 2
// baseline (155.561 us; speedup 1.0000x reference)
//
#include <hip/hip_runtime.h>

#define NB 32
#define WAVES_PER_BLOCK 4

__device__ __forceinline__ float clamp01(float x) {
    return fminf(fmaxf(x, 0.0f), 1.0f);
}

// One 64-lane wave per (b,s) token; 4 tokens per 256-thread block.
// W lives ONLY in registers: lane (g = lw>>3, c = lw&7) holds
// wr[k] = W[row k*8+g][cols 4c..4c+3] for k = 0..3.
// Inflow (W @ h) is computed as per-lane partials over the lane's 4 cols,
// reduced across the 8 lanes of a column-group via shfl_xor(1,2,4).
// No W staging to LDS at all -> LDS 4.6 KB/block, launch_bounds(256,8)
// caps VGPRs at 64 for 32 waves/CU.
__global__ __launch_bounds__(256, 8) void biotoken_step(
    const float* __restrict__ h,
    const float* __restrict__ W,
    const float* __restrict__ stim,
    float* __restrict__ out_h,
    float* __restrict__ out_W)
{
    const int lw    = threadIdx.x & 63;   // lane in wave
    const int wave  = threadIdx.x >> 6;   // 0..3
    const int token = blockIdx.x * WAVES_PER_BLOCK + wave;
    const int g     = lw >> 3;            // row group: lane's rows are k*8+g
    const int c     = lw & 7;             // col group: lane's cols are 4c..4c+3

    __shared__ float s_hin [WAVES_PER_BLOCK][NB * 4];
    __shared__ float s_hnew[WAVES_PER_BLOCK][NB * 4];
    __shared__ float s_stim[WAVES_PER_BLOCK][NB];

    const float4* Wt = (const float4*)(W + (size_t)token * (NB * NB)); // 256 float4
    const float4* ht = (const float4*)(h + (size_t)token * (NB * 4));  // 32 float4
    const float*  st = stim + (size_t)token * NB;

    // ---- stage: W -> registers only; h & stim -> LDS ----
    float4 wr[4];
    wr[0] = Wt[0 * 64 + lw];
    wr[1] = Wt[1 * 64 + lw];
    wr[2] = Wt[2 * 64 + lw];
    wr[3] = Wt[3 * 64 + lw];

    if (lw < NB) {
        ((float4*)s_hin[wave])[lw] = ht[lw];
        s_stim[wave][lw] = st[lw];
    }
    __syncthreads();

    const float* shin = s_hin[wave];

    // ---- pass 1: inflow partials over this lane's 4 columns ----
    const float4 hj0 = ((const float4*)shin)[4 * c + 0];
    const float4 hj1 = ((const float4*)shin)[4 * c + 1];
    const float4 hj2 = ((const float4*)shin)[4 * c + 2];
    const float4 hj3 = ((const float4*)shin)[4 * c + 3];

    float aE[4], aP[4], aG[4], aL[4], aT[4];
    #pragma unroll
    for (int k = 0; k < 4; ++k) {
        const int r = k * 8 + g;
        const float* wp = (const float*)&wr[k];
        const float w0 = (4 * c + 0 == r) ? 0.0f : wp[0];  // zero self-connection
        const float w1 = (4 * c + 1 == r) ? 0.0f : wp[1];
        const float w2 = (4 * c + 2 == r) ? 0.0f : wp[2];
        const float w3 = (4 * c + 3 == r) ? 0.0f : wp[3];
        aE[k] = fmaf(w3, hj3.x, fmaf(w2, hj2.x, fmaf(w1, hj1.x, w0 * hj0.x)));
        aP[k] = fmaf(w3, hj3.y, fmaf(w2, hj2.y, fmaf(w1, hj1.y, w0 * hj0.y)));
        aG[k] = fmaf(w3, hj3.z, fmaf(w2, hj2.z, fmaf(w1, hj1.z, w0 * hj0.z)));
        aL[k] = fmaf(w3, hj3.w, fmaf(w2, hj2.w, fmaf(w1, hj1.w, w0 * hj0.w)));
        aT[k] = (w0 + w1) + (w2 + w3);
    }

    // ---- butterfly reduce across the 8 lanes of the column group ----
    #pragma unroll
    for (int m = 1; m <= 4; m <<= 1) {
        #pragma unroll
        for (int k = 0; k < 4; ++k) {
            aE[k] += __shfl_xor(aE[k], m);
            aP[k] += __shfl_xor(aP[k], m);
            aG[k] += __shfl_xor(aG[k], m);
            aL[k] += __shfl_xor(aL[k], m);
            aT[k] += __shfl_xor(aT[k], m);
        }
    }
    // now every lane in group g holds full inflow sums for rows {k*8+g}

    // ---- EPGL state update for the lane's 4 rows (redundant across group) ----
    float4 hn[4];                          // h_new for rows k*8+g (static indexing)
    #pragma unroll
    for (int k = 0; k < 4; ++k) {
        const int r = k * 8 + g;
        const float4 hi = ((const float4*)shin)[r];
        const float sti = s_stim[wave][r];
        const float inv = 1.0f / (aT[k] + 1e-8f);
        const float En = aE[k] * inv, Pn = aP[k] * inv;
        const float Gn = aG[k] * inv, Ln = aL[k] * inv;
        const float E = hi.x, P = hi.y, G = hi.z, L = hi.w;

        const float E_new = clamp01(E + 0.3f * sti - 0.4f * P - 0.2f * G);
        const float P_new = clamp01(P + 0.5f * sti + 0.3f * (Pn - P) - 0.2f * E);
        const float G_new = clamp01(G + 0.4f * E * (1.0f - P) + 0.2f * (Gn - G) - 0.3f * P);
        const float good  = 0.5f * En + 0.5f * Gn;
        const float L_new = clamp01(L + 0.4f * good + 0.3f * (Ln - L) - 0.3f * P);
        hn[k] = make_float4(E_new, P_new, G_new, L_new);
    }

    // ---- publish h_new: lane with c == k writes row k*8+g (each row once) ----
    if (c < 4) {
        const float4 a   = (c & 1) ? hn[1] : hn[0];     // static indices,
        const float4 b   = (c & 1) ? hn[3] : hn[2];     // runtime condition
        const float4 sel = (c & 2) ? b : a;             // -> cndmask chain
        const int r = c * 8 + g;
        ((float4*)s_hnew[wave])[r] = sel;
        ((float4*)(out_h + (size_t)token * (NB * 4)))[r] = sel;
    }
    __syncthreads();

    // ---- pass 2: W_new. Rows come from registers (hn[k]), cols from LDS ----
    const float* shn = s_hnew[wave];
    const float4 qj0 = ((const float4*)shn)[4 * c + 0];
    const float4 qj1 = ((const float4*)shn)[4 * c + 1];
    const float4 qj2 = ((const float4*)shn)[4 * c + 2];
    const float4 qj3 = ((const float4*)shn)[4 * c + 3];

    float4* outWt = (float4*)(out_W + (size_t)token * (NB * NB));
    #pragma unroll
    for (int k = 0; k < 4; ++k) {
        const int r  = k * 8 + g;
        const float4 hr = hn[k];
        const float  Lr = hr.w;
        const float* wp = (const float*)&wr[k];
        float4 res;
        float* resp = &res.x;
        const float4 qj[4] = { qj0, qj1, qj2, qj3 };   // static-indexed below
        #pragma unroll
        for (int e = 0; e < 4; ++e) {
            const int j = 4 * c + e;
            const float4 hj = qj[e];
            const float dx = hr.x - hj.x;
            const float dy = hr.y - hj.y;
            const float dz = hr.z - hj.z;
            const float dw = hr.w - hj.w;
            const float sq = dx * dx + dy * dy + dz * dz + dw * dw;
            const float dist = sqrtf(sq);               // sqrt(0)=0 matches ref
            const float mutual = 0.5f * (Lr + hj.w);
            float wn = 0.95f * wp[e] + 0.1f * mutual * dist;
            wn = clamp01(wn);
            resp[e] = (j == r) ? 0.0f : wn;             // zero diagonal
        }
        outWt[k * 64 + lw] = res;
    }
}

extern "C" void kernel_launch(void* const* d_in, const int* in_sizes, int n_in,
                              void* d_out, int out_size, void* d_ws, size_t ws_size,
                              hipStream_t stream) {
    const float* h    = (const float*)d_in[0];  // [8,2048,32,4]
    const float* W    = (const float*)d_in[1];  // [8,2048,32,32]
    const float* stim = (const float*)d_in[2];  // [8,2048,32]

    const int tokens = in_sizes[2] / NB;        // 16384
    float* out_h = (float*)d_out;               // [8,2048,32,4]
    float* out_W = (float*)d_out + (size_t)tokens * NB * 4;  // [8,2048,32,32]

    const int blocks = tokens / WAVES_PER_BLOCK; // 4096
    biotoken_step<<<blocks, 256, 0, stream>>>(h, W, stim, out_h, out_W);
}

// Round 4
// 136.789 us; speedup vs baseline: 1.1372x; 1.1372x over previous
//
#include <hip/hip_runtime.h>

#define NB 32
#define WAVES_PER_BLOCK 4

typedef float nfloat4 __attribute__((ext_vector_type(4)));  // native vec for nt-store

__device__ __forceinline__ void nt_store4(const float4& v, float4* p) {
    __builtin_nontemporal_store(*(const nfloat4*)&v, (nfloat4*)p);
}

__device__ __forceinline__ float clamp01(float x) {
    return fminf(fmaxf(x, 0.0f), 1.0f);
}

// One 64-lane wave per (b,s) token; 4 tokens per 256-thread block.
// ALL LDS here is wave-private (every array indexed by [wave]), so there
// are NO __syncthreads: waves proceed fully decoupled. Within a wave,
// DS ops complete in order and the compiler inserts lgkmcnt waits for
// aliasing LDS accesses, which is all the ordering we need.
// W is held in registers between the staging load and the W_new write
// (same lane owns the same 4 float4s in both passes); a padded LDS copy
// (row stride 33 -> conflict-free row reads) serves the inflow pass.
// LDS = 21 KB/block -> 6 blocks/CU; launch_bounds(256,6) = 24 waves/CU.
__global__ __launch_bounds__(256, 6) void biotoken_step(
    const float* __restrict__ h,
    const float* __restrict__ W,
    const float* __restrict__ stim,
    float* __restrict__ out_h,
    float* __restrict__ out_W)
{
    const int lw    = threadIdx.x & 63;   // lane in wave
    const int wave  = threadIdx.x >> 6;   // 0..3
    const int token = blockIdx.x * WAVES_PER_BLOCK + wave;
    const int i     = lw & 31;            // row this lane owns
    const int half  = lw >> 5;            // j-range selector in pass 1

    __shared__ float s_hin [WAVES_PER_BLOCK][NB * 4];
    __shared__ float s_hnew[WAVES_PER_BLOCK][NB * 4];
    __shared__ float s_W   [WAVES_PER_BLOCK][NB * 33];   // +1 pad per row

    const float4* Wt = (const float4*)(W + (size_t)token * (NB * NB)); // 256 float4
    const float4* ht = (const float4*)(h + (size_t)token * (NB * 4));  // 32 float4

    // ---- stage: W -> registers (and padded LDS), h -> LDS, stim -> reg ----
    // float4 index m = k*64+lw : row = m>>3, col = (m&7)*4
    float4 wr[4];
    wr[0] = Wt[0 * 64 + lw];
    wr[1] = Wt[1 * 64 + lw];
    wr[2] = Wt[2 * 64 + lw];
    wr[3] = Wt[3 * 64 + lw];
    const float sti = stim[(size_t)token * NB + i];   // both halves same 128B

    if (lw < NB) {
        ((float4*)s_hin[wave])[lw] = ht[lw];
    }

    {
        float* sw = s_W[wave];
        const int g = lw >> 3;          // row within 8-row group
        const int c = (lw & 7) * 4;     // starting col
        #pragma unroll
        for (int k = 0; k < 4; ++k) {
            const int r = k * 8 + g;
            const float* wp = (const float*)&wr[k];
            sw[r * 33 + c + 0] = wp[0];
            sw[r * 33 + c + 1] = wp[1];
            sw[r * 33 + c + 2] = wp[2];
            sw[r * 33 + c + 3] = wp[3];
        }
    }
    __builtin_amdgcn_wave_barrier();    // scheduling fence only (free)

    // ---- pass 1: inflow. lane (i, half) sums 16 j's ----
    const float* sw   = s_W[wave];
    const float* shin = s_hin[wave];

    float accE = 0.f, accP = 0.f, accG = 0.f, accL = 0.f, tot = 0.f;
    #pragma unroll
    for (int t = 0; t < 16; ++t) {
        const int j = half * 16 + t;
        float w = sw[i * 33 + j];
        w = (j == i) ? 0.0f : w;                 // zero self-connection
        const float4 hj = *(const float4*)&shin[j * 4];
        accE = fmaf(w, hj.x, accE);
        accP = fmaf(w, hj.y, accP);
        accG = fmaf(w, hj.z, accG);
        accL = fmaf(w, hj.w, accL);
        tot += w;
    }
    accE += __shfl_xor(accE, 32);
    accP += __shfl_xor(accP, 32);
    accG += __shfl_xor(accG, 32);
    accL += __shfl_xor(accL, 32);
    tot  += __shfl_xor(tot,  32);

    const float inv = 1.0f / (tot + 1e-8f);
    const float En = accE * inv, Pn = accP * inv, Gn = accG * inv, Ln = accL * inv;

    // ---- EPGL state update (computed redundantly in both halves) ----
    const float4 hi = *(const float4*)&shin[i * 4];
    const float E = hi.x, P = hi.y, G = hi.z, L = hi.w;

    const float E_new = clamp01(E + 0.3f * sti - 0.4f * P - 0.2f * G);
    const float P_new = clamp01(P + 0.5f * sti + 0.3f * (Pn - P) - 0.2f * E);
    const float G_new = clamp01(G + 0.4f * E * (1.0f - P) + 0.2f * (Gn - G) - 0.3f * P);
    const float good  = 0.5f * En + 0.5f * Gn;
    const float L_new = clamp01(L + 0.4f * good + 0.3f * (Ln - L) - 0.3f * P);

    if (half == 0) {
        const float4 hn = make_float4(E_new, P_new, G_new, L_new);
        ((float4*)s_hnew[wave])[i] = hn;
        nt_store4(hn, &((float4*)(out_h + (size_t)token * (NB * 4)))[i]);
    }
    __builtin_amdgcn_wave_barrier();    // scheduling fence only (free)

    // ---- pass 2: W_new. pairwise distance + update, W from registers ----
    const float* shn = s_hnew[wave];
    float4* outWt = (float4*)(out_W + (size_t)token * (NB * NB));

    // hj columns depend only on (lw & 7), NOT on k (m = k*64+lw, 64 % 8 == 0):
    // hoist the 4 column float4s out of the k loop.
    const int jb0 = (lw & 7) * 4;
    float4 hjv[4];
    #pragma unroll
    for (int e = 0; e < 4; ++e) {
        hjv[e] = *(const float4*)&shn[(jb0 + e) * 4];
    }

    #pragma unroll
    for (int k = 0; k < 4; ++k) {
        const int m  = k * 64 + lw;       // float4 index in token's W
        const int r  = m >> 3;            // row
        const float4 hr = *(const float4*)&shn[r * 4];
        const float  Lr = hr.w;
        const float* wp = (const float*)&wr[k];
        float4 res;
        float* resp = &res.x;
        #pragma unroll
        for (int e = 0; e < 4; ++e) {
            const int j = jb0 + e;
            const float4 hj = hjv[e];
            const float dx = hr.x - hj.x;
            const float dy = hr.y - hj.y;
            const float dz = hr.z - hj.z;
            const float dw = hr.w - hj.w;
            const float sq = dx * dx + dy * dy + dz * dz + dw * dw;
            const float dist = sqrtf(sq);               // sqrt(0)=0 matches ref
            const float mutual = 0.5f * (Lr + hj.w);
            float wn = 0.95f * wp[e] + 0.1f * mutual * dist;
            wn = clamp01(wn);
            resp[e] = (j == r) ? 0.0f : wn;             // zero diagonal
        }
        nt_store4(res, &outWt[m]);
    }
}

extern "C" void kernel_launch(void* const* d_in, const int* in_sizes, int n_in,
                              void* d_out, int out_size, void* d_ws, size_t ws_size,
                              hipStream_t stream) {
    const float* h    = (const float*)d_in[0];  // [8,2048,32,4]
    const float* W    = (const float*)d_in[1];  // [8,2048,32,32]
    const float* stim = (const float*)d_in[2];  // [8,2048,32]

    const int tokens = in_sizes[2] / NB;        // 16384
    float* out_h = (float*)d_out;               // [8,2048,32,4]
    float* out_W = (float*)d_out + (size_t)tokens * NB * 4;  // [8,2048,32,32]

    const int blocks = tokens / WAVES_PER_BLOCK; // 4096
    biotoken_step<<<blocks, 256, 0, stream>>>(h, W, stim, out_h, out_W);
}